// Round 4
// baseline (244.246 us; speedup 1.0000x reference)
//
#include <hip/hip_runtime.h>
#include <hip/hip_bf16.h>

// DiagWinAttention: nw=4096, N=64 tokens, E=96 = 6 heads x 16. fp32 I/O.
// 1 block = 1 window, 384 threads = 6 waves, wave h = head h.
// Swapped QK^T => P lands in PV A-fragment layout; PV fused per row-tile so
// P never exceeds 8 VGPRs. Bias table in LDS (saves 28 VGPRs). Target: 64
// VGPRs -> 8 waves/SIMD -> 5 blocks/CU.

typedef short v4s __attribute__((ext_vector_type(4)));
typedef float v4f __attribute__((ext_vector_type(4)));

#define MFMA16(A, B, C) __builtin_amdgcn_mfma_f32_16x16x16bf16_1k(A, B, C, 0, 0, 0)

static __device__ __forceinline__ ushort f2b(float x) {
  union { __hip_bfloat16 h; ushort u; } c; c.h = __float2bfloat16(x); return c.u;
}
static __device__ __forceinline__ float b2f(ushort u) {
  union { ushort u; __hip_bfloat16 h; } c; c.u = u; return __bfloat162float(c.h);
}

#define SMS 68      // mask LDS row stride (bf16)
#define SXS 100     // X row stride (bf16); also fp32 Y stride in reuse
#define SBS 228     // bias table per-head stride (fp32)
#define LOG2E 1.4426950408889634f

__global__ __launch_bounds__(384, 8)
void winattn_kernel(const float* __restrict__ gQ, const float* __restrict__ gK,
                    const float* __restrict__ gV, const float* __restrict__ gM,
                    const float* __restrict__ gBT, const float* __restrict__ gGa,
                    const float* __restrict__ gBe, const float* __restrict__ gW,
                    const float* __restrict__ gPb, float* __restrict__ gO)
{
  __shared__ __align__(16) ushort sM[64 * SMS];  //  8704 B mask * log2e (bf16)
  __shared__ __align__(16) ushort sX[64 * SXS];  // 12800 B X -> Xn -> fp32 Y halves
  __shared__ float sB[6 * SBS];                  //  5472 B bias tables * log2e
  __shared__ float sPS[64 * 13];                 //  3328 B LN partials
  // total 30304 B -> 5 blocks/CU (151.5 KB)

  const int tid  = threadIdx.x;
  const int w    = blockIdx.x;
  const int wave = tid >> 6;         // head
  const int lane = tid & 63;
  const int l15  = lane & 15;
  const int g    = lane >> 4;
  const size_t base = (size_t)w * 6144;

  // ---- V fragments (B-operand): vf[kk] reg j = V[16kk+4g+j][16*wave+l15] ----
  v4s vf[4];
  {
    const float* vp = gV + base + 16 * wave + l15;
    #pragma unroll
    for (int kk = 0; kk < 4; ++kk) {
      float a0 = vp[(16 * kk + 4 * g + 0) * 96];
      float a1 = vp[(16 * kk + 4 * g + 1) * 96];
      float a2 = vp[(16 * kk + 4 * g + 2) * 96];
      float a3 = vp[(16 * kk + 4 * g + 3) * 96];
      v4s t; t[0] = (short)f2b(a0); t[1] = (short)f2b(a1);
      t[2] = (short)f2b(a2); t[3] = (short)f2b(a3);
      vf[kk] = t;
    }
  }

  // ---- Q,K fragments direct from global (A-operand rows) ----
  v4s aq[4], bk[4];
  {
    const float QS = 0.25f * LOG2E;              // scale * log2e folded into Q
    const float* qp = gQ + base + 16 * wave + 4 * g;
    const float* kp = gK + base + 16 * wave + 4 * g;
    #pragma unroll
    for (int t = 0; t < 4; ++t) {
      float4 qv = *(const float4*)(qp + (16 * t + l15) * 96);
      float4 kv = *(const float4*)(kp + (16 * t + l15) * 96);
      v4s a; a[0] = (short)f2b(qv.x * QS); a[1] = (short)f2b(qv.y * QS);
      a[2] = (short)f2b(qv.z * QS); a[3] = (short)f2b(qv.w * QS);
      aq[t] = a;
      v4s b; b[0] = (short)f2b(kv.x); b[1] = (short)f2b(kv.y);
      b[2] = (short)f2b(kv.z); b[3] = (short)f2b(kv.w);
      bk[t] = b;
    }
  }

  // ---- mask -> LDS (bf16, * log2e) ----
  {
    const float4* m4 = (const float4*)(gM + (size_t)w * 4096);
    #pragma unroll
    for (int i = 0; i < 3; ++i) {
      const int idx = tid + i * 384;
      if (idx < 1024) {
        const int r = idx >> 4, c0 = (idx & 15) * 4;
        float4 a = m4[idx];
        ushort4 u;
        u.x = f2b(a.x * LOG2E); u.y = f2b(a.y * LOG2E);
        u.z = f2b(a.z * LOG2E); u.w = f2b(a.w * LOG2E);
        *(ushort4*)&sM[r * SMS + c0] = u;
      }
    }
  }
  // ---- bias table -> LDS (fp32, * log2e, per-head layout) ----
  for (int i = tid; i < 1350; i += 384) {
    const int idx = i / 6, h = i - 6 * idx;
    sB[h * SBS + idx] = gBT[i] * LOG2E;
  }
  __syncthreads();

  // ---- fused attention: per row-tile QK^T -> softmax -> PV accumulate ----
  // acc tile (ct): lane(l15,g) reg rg = S[16rt+l15][16ct+4g+rg] (log2e-scaled)
  const float* bh = &sB[wave * SBS];
  const int bb = ((l15 >> 3) - (g >> 1)) * 15 + (l15 & 7) - 4 * (g & 1) + 112;
  v4f oa[4];
  #pragma unroll
  for (int mt = 0; mt < 4; ++mt) { v4f z = {0.f, 0.f, 0.f, 0.f}; oa[mt] = z; }

  #pragma unroll
  for (int rt = 0; rt < 4; ++rt) {
    v4f acc[4];
    #pragma unroll
    for (int ct = 0; ct < 4; ++ct) {
      ushort4 u = *(const ushort4*)&sM[(16 * rt + l15) * SMS + 16 * ct + 4 * g];
      const int b0 = bb + 30 * (rt - ct);
      v4f ini = {bh[b0 - 0] + b2f(u.x), bh[b0 - 1] + b2f(u.y),
                 bh[b0 - 2] + b2f(u.z), bh[b0 - 3] + b2f(u.w)};
      acc[ct] = ini;
    }
    #pragma unroll
    for (int ct = 0; ct < 4; ++ct) acc[ct] = MFMA16(bk[ct], aq[rt], acc[ct]);

    float s = 0.f;
    #pragma unroll
    for (int ct = 0; ct < 4; ++ct) {
      float e0 = exp2f(acc[ct][0]);
      float e1 = exp2f(acc[ct][1]);
      float e2 = exp2f(acc[ct][2]);
      float e3 = exp2f(acc[ct][3]);
      v4f e = {e0, e1, e2, e3};
      acc[ct] = e;
      s += (e0 + e1) + (e2 + e3);
    }
    s += __shfl_xor(s, 16, 64);
    s += __shfl_xor(s, 32, 64);
    const float r = __builtin_amdgcn_rcpf(s);
    // P row-block (bf16) -> 4 PV MFMAs into oa[rt]; pa regs recycled per rt
    v4s pa[4];
    #pragma unroll
    for (int ct = 0; ct < 4; ++ct) {
      v4s t;
      t[0] = (short)f2b(acc[ct][0] * r); t[1] = (short)f2b(acc[ct][1] * r);
      t[2] = (short)f2b(acc[ct][2] * r); t[3] = (short)f2b(acc[ct][3] * r);
      pa[ct] = t;
    }
    #pragma unroll
    for (int ct = 0; ct < 4; ++ct) oa[rt] = MFMA16(pa[ct], vf[ct], oa[rt]);
  }

  // ---- X = O + q*scale (bf16) to LDS; residual q loaded at use (L2-hot) ----
  {
    const float* qr = gQ + base + 16 * wave + l15;
    #pragma unroll
    for (int mt = 0; mt < 4; ++mt)
      #pragma unroll
      for (int rg = 0; rg < 4; ++rg) {
        const int row = 16 * mt + 4 * g + rg;
        sX[row * SXS + 16 * wave + l15] = f2b(oa[mt][rg] + 0.25f * qr[row * 96]);
      }
  }
  __syncthreads();

  // ---- W fragments + proj bias prefetch (L2-hot; consumed after LN) ----
  const int oc = 16 * wave + l15;
  v4s wfr[6];
  #pragma unroll
  for (int kk = 0; kk < 6; ++kk) {
    float4 wv = *(const float4*)(gW + oc * 96 + kk * 16 + 4 * g);
    v4s t; t[0] = (short)f2b(wv.x); t[1] = (short)f2b(wv.y);
    t[2] = (short)f2b(wv.z); t[3] = (short)f2b(wv.w);
    wfr[kk] = t;
  }
  const float pb = gPb[oc];

  // ---- cooperative LayerNorm: row = lane, strip = wave; in-place ----
  float xs[16];
  {
    const ushort* xr = &sX[lane * SXS + 16 * wave];
    #pragma unroll
    for (int i = 0; i < 4; ++i) {
      ushort4 u = *(const ushort4*)&xr[i * 4];
      xs[4 * i + 0] = b2f(u.x); xs[4 * i + 1] = b2f(u.y);
      xs[4 * i + 2] = b2f(u.z); xs[4 * i + 3] = b2f(u.w);
    }
    float s1 = 0.f, s2 = 0.f;
    #pragma unroll
    for (int i = 0; i < 16; ++i) { s1 += xs[i]; s2 += xs[i] * xs[i]; }
    sPS[lane * 13 + 2 * wave + 0] = s1;
    sPS[lane * 13 + 2 * wave + 1] = s2;
  }
  __syncthreads();
  {
    float s1 = 0.f, s2 = 0.f;
    #pragma unroll
    for (int t = 0; t < 6; ++t) {
      s1 += sPS[lane * 13 + 2 * t];
      s2 += sPS[lane * 13 + 2 * t + 1];
    }
    const float mu  = s1 * (1.f / 96.f);
    const float var = s2 * (1.f / 96.f) - mu * mu;
    const float rsig = __builtin_amdgcn_rsqf(var + 1e-5f);
    const float* gp = gGa + 16 * wave;
    const float* bp = gBe + 16 * wave;
    ushort* xr = &sX[lane * SXS + 16 * wave];
    #pragma unroll
    for (int i = 0; i < 4; ++i) {
      ushort4 o;
      o.x = f2b((xs[4 * i + 0] - mu) * rsig * gp[4 * i + 0] + bp[4 * i + 0]);
      o.y = f2b((xs[4 * i + 1] - mu) * rsig * gp[4 * i + 1] + bp[4 * i + 1]);
      o.z = f2b((xs[4 * i + 2] - mu) * rsig * gp[4 * i + 2] + bp[4 * i + 2]);
      o.w = f2b((xs[4 * i + 3] - mu) * rsig * gp[4 * i + 3] + bp[4 * i + 3]);
      *(ushort4*)&xr[i * 4] = o;
    }
  }
  __syncthreads();

  // ---- projection: Y = Xn @ W^T + b ----
  v4f ya[4];
  #pragma unroll
  for (int mt = 0; mt < 4; ++mt) { v4f z = {0.f, 0.f, 0.f, 0.f}; ya[mt] = z; }
  #pragma unroll
  for (int kk = 0; kk < 6; ++kk)
    #pragma unroll
    for (int mt = 0; mt < 4; ++mt) {
      v4s xa = *(const v4s*)&sX[(16 * mt + l15) * SXS + 16 * kk + 4 * g];
      ya[mt] = MFMA16(xa, wfr[kk], ya[mt]);
    }

  // ---- staged coalesced output: two 32-row halves through LDS (stride 100) ----
  __syncthreads();                       // all proj LDS reads done
  float* sY = (float*)sX;                // [32][SXS] fp32 = 12800 B
  float4* o4 = (float4*)(gO + base);
  #pragma unroll
  for (int mt = 0; mt < 2; ++mt)
    #pragma unroll
    for (int rg = 0; rg < 4; ++rg)
      sY[(16 * mt + 4 * g + rg) * SXS + oc] = ya[mt][rg] + pb;
  __syncthreads();
  #pragma unroll
  for (int i = 0; i < 2; ++i) {
    const int idx = tid + i * 384;
    const int r = idx / 24, c = idx % 24;
    o4[idx] = *(const float4*)&sY[r * SXS + c * 4];
  }
  __syncthreads();
  #pragma unroll
  for (int mt = 2; mt < 4; ++mt)
    #pragma unroll
    for (int rg = 0; rg < 4; ++rg)
      sY[(16 * (mt - 2) + 4 * g + rg) * SXS + oc] = ya[mt][rg] + pb;
  __syncthreads();
  #pragma unroll
  for (int i = 0; i < 2; ++i) {
    const int idx = tid + i * 384;
    const int r = idx / 24, c = idx % 24;
    o4[768 + idx] = *(const float4*)&sY[r * SXS + c * 4];
  }
}

extern "C" void kernel_launch(void* const* d_in, const int* in_sizes, int n_in,
                              void* d_out, int out_size, void* d_ws, size_t ws_size,
                              hipStream_t stream) {
  (void)in_sizes; (void)n_in; (void)out_size; (void)d_ws; (void)ws_size;
  winattn_kernel<<<dim3(4096), dim3(384), 0, stream>>>(
      (const float*)d_in[0], (const float*)d_in[1], (const float*)d_in[2],
      (const float*)d_in[3], (const float*)d_in[4], (const float*)d_in[5],
      (const float*)d_in[6], (const float*)d_in[7], (const float*)d_in[8],
      (float*)d_out);
}

// Round 5
// 162.017 us; speedup vs baseline: 1.5075x; 1.5075x over previous
//
#include <hip/hip_runtime.h>
#include <hip/hip_bf16.h>

// DiagWinAttention: nw=4096, N=64 tokens, E=96 = 6 heads x 16. fp32 I/O.
// 1 block = 1 window, 384 threads = 6 waves, wave h = head h.
// Swapped QK^T => P lands in PV A-fragment layout; PV fused per row-tile.
// Bias table + mask in LDS. launch_bounds(384,5): VGPR cap 102 -> no spill
// (R3/R4 post-mortem: caps of 64/32 caused 50-350MB scratch traffic),
// 5 waves/SIMD for latency hiding.

typedef short v4s __attribute__((ext_vector_type(4)));
typedef float v4f __attribute__((ext_vector_type(4)));

#define MFMA16(A, B, C) __builtin_amdgcn_mfma_f32_16x16x16bf16_1k(A, B, C, 0, 0, 0)

static __device__ __forceinline__ ushort f2b(float x) {
  union { __hip_bfloat16 h; ushort u; } c; c.h = __float2bfloat16(x); return c.u;
}
static __device__ __forceinline__ float b2f(ushort u) {
  union { ushort u; __hip_bfloat16 h; } c; c.u = u; return __bfloat162float(c.h);
}

#define SMS 68      // mask LDS row stride (bf16)
#define SXS 100     // X row stride (bf16); also fp32 Y stride in reuse
#define SBS 228     // bias table per-head stride (fp32)
#define LOG2E 1.4426950408889634f

__global__ __launch_bounds__(384, 5)
void winattn_kernel(const float* __restrict__ gQ, const float* __restrict__ gK,
                    const float* __restrict__ gV, const float* __restrict__ gM,
                    const float* __restrict__ gBT, const float* __restrict__ gGa,
                    const float* __restrict__ gBe, const float* __restrict__ gW,
                    const float* __restrict__ gPb, float* __restrict__ gO)
{
  __shared__ __align__(16) ushort sM[64 * SMS];  //  8704 B mask * log2e (bf16)
  __shared__ __align__(16) ushort sX[64 * SXS];  // 12800 B X -> Xn -> fp32 Y halves
  __shared__ float sB[6 * SBS];                  //  5472 B bias tables * log2e
  __shared__ float sPS[64 * 13];                 //  3328 B LN partials
  // total 30304 B -> 4+ blocks/CU LDS-wise

  const int tid  = threadIdx.x;
  const int w    = blockIdx.x;
  const int wave = tid >> 6;         // head
  const int lane = tid & 63;
  const int l15  = lane & 15;
  const int g    = lane >> 4;
  const size_t base = (size_t)w * 6144;

  // ---- V fragments (B-operand): vf[kk] reg j = V[16kk+4g+j][16*wave+l15] ----
  v4s vf[4];
  {
    const float* vp = gV + base + 16 * wave + l15;
    #pragma unroll
    for (int kk = 0; kk < 4; ++kk) {
      float a0 = vp[(16 * kk + 4 * g + 0) * 96];
      float a1 = vp[(16 * kk + 4 * g + 1) * 96];
      float a2 = vp[(16 * kk + 4 * g + 2) * 96];
      float a3 = vp[(16 * kk + 4 * g + 3) * 96];
      v4s t; t[0] = (short)f2b(a0); t[1] = (short)f2b(a1);
      t[2] = (short)f2b(a2); t[3] = (short)f2b(a3);
      vf[kk] = t;
    }
  }

  // ---- Q,K fragments direct from global (A-operand rows) ----
  v4s aq[4], bk[4];
  {
    const float QS = 0.25f * LOG2E;              // scale * log2e folded into Q
    const float* qp = gQ + base + 16 * wave + 4 * g;
    const float* kp = gK + base + 16 * wave + 4 * g;
    #pragma unroll
    for (int t = 0; t < 4; ++t) {
      float4 qv = *(const float4*)(qp + (16 * t + l15) * 96);
      float4 kv = *(const float4*)(kp + (16 * t + l15) * 96);
      v4s a; a[0] = (short)f2b(qv.x * QS); a[1] = (short)f2b(qv.y * QS);
      a[2] = (short)f2b(qv.z * QS); a[3] = (short)f2b(qv.w * QS);
      aq[t] = a;
      v4s b; b[0] = (short)f2b(kv.x); b[1] = (short)f2b(kv.y);
      b[2] = (short)f2b(kv.z); b[3] = (short)f2b(kv.w);
      bk[t] = b;
    }
  }

  // ---- mask -> LDS (bf16, * log2e) ----
  {
    const float4* m4 = (const float4*)(gM + (size_t)w * 4096);
    #pragma unroll
    for (int i = 0; i < 3; ++i) {
      const int idx = tid + i * 384;
      if (idx < 1024) {
        const int r = idx >> 4, c0 = (idx & 15) * 4;
        float4 a = m4[idx];
        ushort4 u;
        u.x = f2b(a.x * LOG2E); u.y = f2b(a.y * LOG2E);
        u.z = f2b(a.z * LOG2E); u.w = f2b(a.w * LOG2E);
        *(ushort4*)&sM[r * SMS + c0] = u;
      }
    }
  }
  // ---- bias table -> LDS (fp32, * log2e, per-head layout) ----
  for (int i = tid; i < 1350; i += 384) {
    const int idx = i / 6, h = i - 6 * idx;
    sB[h * SBS + idx] = gBT[i] * LOG2E;
  }
  __syncthreads();

  // ---- fused attention: per row-tile QK^T -> softmax -> PV accumulate ----
  // acc tile (ct): lane(l15,g) reg rg = S[16rt+l15][16ct+4g+rg] (log2e-scaled)
  const float* bh = &sB[wave * SBS];
  const int bb = ((l15 >> 3) - (g >> 1)) * 15 + (l15 & 7) - 4 * (g & 1) + 112;
  v4f oa[4];
  #pragma unroll
  for (int mt = 0; mt < 4; ++mt) { v4f z = {0.f, 0.f, 0.f, 0.f}; oa[mt] = z; }

  #pragma unroll
  for (int rt = 0; rt < 4; ++rt) {
    v4f acc[4];
    #pragma unroll
    for (int ct = 0; ct < 4; ++ct) {
      ushort4 u = *(const ushort4*)&sM[(16 * rt + l15) * SMS + 16 * ct + 4 * g];
      const int b0 = bb + 30 * (rt - ct);
      v4f ini = {bh[b0 - 0] + b2f(u.x), bh[b0 - 1] + b2f(u.y),
                 bh[b0 - 2] + b2f(u.z), bh[b0 - 3] + b2f(u.w)};
      acc[ct] = ini;
    }
    #pragma unroll
    for (int ct = 0; ct < 4; ++ct) acc[ct] = MFMA16(bk[ct], aq[rt], acc[ct]);

    float s = 0.f;
    #pragma unroll
    for (int ct = 0; ct < 4; ++ct) {
      float e0 = exp2f(acc[ct][0]);
      float e1 = exp2f(acc[ct][1]);
      float e2 = exp2f(acc[ct][2]);
      float e3 = exp2f(acc[ct][3]);
      v4f e = {e0, e1, e2, e3};
      acc[ct] = e;
      s += (e0 + e1) + (e2 + e3);
    }
    s += __shfl_xor(s, 16, 64);
    s += __shfl_xor(s, 32, 64);
    const float r = __builtin_amdgcn_rcpf(s);
    // P row-block (bf16) -> 4 PV MFMAs into oa[rt]; pa regs recycled per rt
    v4s pa[4];
    #pragma unroll
    for (int ct = 0; ct < 4; ++ct) {
      v4s t;
      t[0] = (short)f2b(acc[ct][0] * r); t[1] = (short)f2b(acc[ct][1] * r);
      t[2] = (short)f2b(acc[ct][2] * r); t[3] = (short)f2b(acc[ct][3] * r);
      pa[ct] = t;
    }
    #pragma unroll
    for (int ct = 0; ct < 4; ++ct) oa[rt] = MFMA16(pa[ct], vf[ct], oa[rt]);
  }

  // ---- X = O + q*scale (bf16) to LDS; residual q loaded at use (L2-hot) ----
  {
    const float* qr = gQ + base + 16 * wave + l15;
    #pragma unroll
    for (int mt = 0; mt < 4; ++mt)
      #pragma unroll
      for (int rg = 0; rg < 4; ++rg) {
        const int row = 16 * mt + 4 * g + rg;
        sX[row * SXS + 16 * wave + l15] = f2b(oa[mt][rg] + 0.25f * qr[row * 96]);
      }
  }
  __syncthreads();

  // ---- W fragments + proj bias prefetch (L2-hot; consumed after LN) ----
  const int oc = 16 * wave + l15;
  v4s wfr[6];
  #pragma unroll
  for (int kk = 0; kk < 6; ++kk) {
    float4 wv = *(const float4*)(gW + oc * 96 + kk * 16 + 4 * g);
    v4s t; t[0] = (short)f2b(wv.x); t[1] = (short)f2b(wv.y);
    t[2] = (short)f2b(wv.z); t[3] = (short)f2b(wv.w);
    wfr[kk] = t;
  }
  const float pb = gPb[oc];

  // ---- cooperative LayerNorm: row = lane, strip = wave; in-place ----
  float xs[16];
  {
    const ushort* xr = &sX[lane * SXS + 16 * wave];
    #pragma unroll
    for (int i = 0; i < 4; ++i) {
      ushort4 u = *(const ushort4*)&xr[i * 4];
      xs[4 * i + 0] = b2f(u.x); xs[4 * i + 1] = b2f(u.y);
      xs[4 * i + 2] = b2f(u.z); xs[4 * i + 3] = b2f(u.w);
    }
    float s1 = 0.f, s2 = 0.f;
    #pragma unroll
    for (int i = 0; i < 16; ++i) { s1 += xs[i]; s2 += xs[i] * xs[i]; }
    sPS[lane * 13 + 2 * wave + 0] = s1;
    sPS[lane * 13 + 2 * wave + 1] = s2;
  }
  __syncthreads();
  {
    float s1 = 0.f, s2 = 0.f;
    #pragma unroll
    for (int t = 0; t < 6; ++t) {
      s1 += sPS[lane * 13 + 2 * t];
      s2 += sPS[lane * 13 + 2 * t + 1];
    }
    const float mu  = s1 * (1.f / 96.f);
    const float var = s2 * (1.f / 96.f) - mu * mu;
    const float rsig = __builtin_amdgcn_rsqf(var + 1e-5f);
    const float* gp = gGa + 16 * wave;
    const float* bp = gBe + 16 * wave;
    ushort* xr = &sX[lane * SXS + 16 * wave];
    #pragma unroll
    for (int i = 0; i < 4; ++i) {
      ushort4 o;
      o.x = f2b((xs[4 * i + 0] - mu) * rsig * gp[4 * i + 0] + bp[4 * i + 0]);
      o.y = f2b((xs[4 * i + 1] - mu) * rsig * gp[4 * i + 1] + bp[4 * i + 1]);
      o.z = f2b((xs[4 * i + 2] - mu) * rsig * gp[4 * i + 2] + bp[4 * i + 2]);
      o.w = f2b((xs[4 * i + 3] - mu) * rsig * gp[4 * i + 3] + bp[4 * i + 3]);
      *(ushort4*)&xr[i * 4] = o;
    }
  }
  __syncthreads();

  // ---- projection: Y = Xn @ W^T + b ----
  v4f ya[4];
  #pragma unroll
  for (int mt = 0; mt < 4; ++mt) { v4f z = {0.f, 0.f, 0.f, 0.f}; ya[mt] = z; }
  #pragma unroll
  for (int kk = 0; kk < 6; ++kk)
    #pragma unroll
    for (int mt = 0; mt < 4; ++mt) {
      v4s xa = *(const v4s*)&sX[(16 * mt + l15) * SXS + 16 * kk + 4 * g];
      ya[mt] = MFMA16(xa, wfr[kk], ya[mt]);
    }

  // ---- staged coalesced output: two 32-row halves through LDS (stride 100) ----
  __syncthreads();                       // all proj LDS reads done
  float* sY = (float*)sX;                // [32][SXS] fp32 = 12800 B
  float4* o4 = (float4*)(gO + base);
  #pragma unroll
  for (int mt = 0; mt < 2; ++mt)
    #pragma unroll
    for (int rg = 0; rg < 4; ++rg)
      sY[(16 * mt + 4 * g + rg) * SXS + oc] = ya[mt][rg] + pb;
  __syncthreads();
  #pragma unroll
  for (int i = 0; i < 2; ++i) {
    const int idx = tid + i * 384;
    const int r = idx / 24, c = idx % 24;
    o4[idx] = *(const float4*)&sY[r * SXS + c * 4];
  }
  __syncthreads();
  #pragma unroll
  for (int mt = 2; mt < 4; ++mt)
    #pragma unroll
    for (int rg = 0; rg < 4; ++rg)
      sY[(16 * (mt - 2) + 4 * g + rg) * SXS + oc] = ya[mt][rg] + pb;
  __syncthreads();
  #pragma unroll
  for (int i = 0; i < 2; ++i) {
    const int idx = tid + i * 384;
    const int r = idx / 24, c = idx % 24;
    o4[768 + idx] = *(const float4*)&sY[r * SXS + c * 4];
  }
}

extern "C" void kernel_launch(void* const* d_in, const int* in_sizes, int n_in,
                              void* d_out, int out_size, void* d_ws, size_t ws_size,
                              hipStream_t stream) {
  (void)in_sizes; (void)n_in; (void)out_size; (void)d_ws; (void)ws_size;
  winattn_kernel<<<dim3(4096), dim3(384), 0, stream>>>(
      (const float*)d_in[0], (const float*)d_in[1], (const float*)d_in[2],
      (const float*)d_in[3], (const float*)d_in[4], (const float*)d_in[5],
      (const float*)d_in[6], (const float*)d_in[7], (const float*)d_in[8],
      (float*)d_out);
}